// Round 6
// baseline (82.200 us; speedup 1.0000x reference)
//
#include <hip/hip_runtime.h>

#define TWO_LOG2E 2.8853901817779268f   // 2*log2(e)
#define LOG2E     1.4426950408889634f

// quad_perm DPP cross-lane (VALU pipe)
template<int CTRL>
__device__ __forceinline__ float dpp_qperm(float x) {
    int r = __builtin_amdgcn_update_dpp(0, __float_as_int(x), CTRL, 0xF, 0xF, true);
    return __int_as_float(r);
}

// One-shot kernel: thread handles 4 items at +64 spacing; a wave covers 256
// consecutive items -> idx loads & stores fold into base+const-offset form.
// TLP via 25k small blocks instead of per-wave pipelining (R2-R5 all ~61us:
// resident waves park on the same vmcnt; block turnover keeps fresh work).
__global__ __launch_bounds__(128) void edge_mlp(
    const float* __restrict__ m,     // [N_NODES, 4, 2]
    const int*   __restrict__ eidx,  // [2, E]
    const float* __restrict__ W1,    // [4, 4, 8]
    const float* __restrict__ b1,    // [4, 8]
    const float* __restrict__ W2,    // [4, 8, 1]
    const float* __restrict__ b2,    // [4, 1]
    float*       __restrict__ out,   // [E, 4]
    const int nE)
{
    const int total = nE * 4;
    // wave (threadIdx>>6) covers items [blk*512 + w*256, +256); lane adds 0..63
    const int t0 = blockIdx.x * 512 + ((threadIdx.x >> 6) << 8) + (threadIdx.x & 63);
    const int c  = threadIdx.x & 3;
    const int cc2 = c * 2;
    const int e0 = t0 >> 2;
    const int* eidx1 = eidx + nE;

    if (t0 + 192 < total) {
        // ---- issue idx loads FIRST (latency covered by weight load+prescale) ----
        int row[4], col[4];
        #pragma unroll
        for (int k = 0; k < 4; ++k) {
            row[k] = __builtin_nontemporal_load(eidx  + e0 + 16 * k); // const offsets
            col[k] = __builtin_nontemporal_load(eidx1 + e0 + 16 * k);
        }

        // ---- per-class weights, prescaled by 2*log2e (independent of idx) ----
        float w1[32];
        #pragma unroll
        for (int k = 0; k < 8; ++k) {
            float4 v = *(const float4*)(W1 + c * 32 + 4 * k);
            w1[4*k+0] = v.x * TWO_LOG2E; w1[4*k+1] = v.y * TWO_LOG2E;
            w1[4*k+2] = v.z * TWO_LOG2E; w1[4*k+3] = v.w * TWO_LOG2E;
        }
        float bb1[8];
        #pragma unroll
        for (int j = 0; j < 8; ++j) bb1[j] = b1[c*8 + j] * TWO_LOG2E;
        float w2[8];
        #pragma unroll
        for (int j = 0; j < 8; ++j) w2[j] = W2[c*8 + j] * TWO_LOG2E;
        const float b2s = b2[c] * TWO_LOG2E;

        // ---- gathers (32-bit voffset: node*32B + c*8B) ----
        float2 mc[4], mr[4];
        #pragma unroll
        for (int k = 0; k < 4; ++k) {
            mc[k] = *(const float2*)(m + (unsigned)col[k] * 8u + cc2);
            mr[k] = *(const float2*)(m + (unsigned)row[k] * 8u + cc2);
        }

        // ---- compute + store ----
        #pragma unroll
        for (int k = 0; k < 4; ++k) {
            float o = b2s;                       // scaled domain (x 2log2e)
            #pragma unroll
            for (int j = 0; j < 8; ++j) {
                float h = bb1[j];
                h = fmaf(mc[k].x, w1[j],      h);
                h = fmaf(mc[k].y, w1[8 + j],  h);
                h = fmaf(mr[k].x, w1[16 + j], h);
                h = fmaf(mr[k].y, w1[24 + j], h);
                const float e = __builtin_amdgcn_exp2f(h);          // e^{2x}
                const float r = __builtin_amdgcn_rcpf(e + 1.0f);
                o = fmaf(fmaf(-2.0f, r, 1.0f), w2[j], o);           // tanh*w2
            }
            // eo = e^{tanh(o_true)} = 2^{log2e - 2log2e * rcp(e^{2 o_true}+1)}
            const float e2 = __builtin_amdgcn_exp2f(o);
            const float r2 = __builtin_amdgcn_rcpf(e2 + 1.0f);
            const float eo = __builtin_amdgcn_exp2f(fmaf(-TWO_LOG2E, r2, LOG2E));
            float s = eo + dpp_qperm<0xB1>(eo);      // xor 1
            s = s + dpp_qperm<0x4E>(s);              // xor 2
            __builtin_nontemporal_store(eo * __builtin_amdgcn_rcpf(s),
                                        out + t0 + 64 * k);          // const offsets
        }
    } else {
        // ---- tail path (bounds-checked per item) ----
        float w1[32];
        #pragma unroll
        for (int k = 0; k < 8; ++k) {
            float4 v = *(const float4*)(W1 + c * 32 + 4 * k);
            w1[4*k+0] = v.x * TWO_LOG2E; w1[4*k+1] = v.y * TWO_LOG2E;
            w1[4*k+2] = v.z * TWO_LOG2E; w1[4*k+3] = v.w * TWO_LOG2E;
        }
        float bb1[8];
        #pragma unroll
        for (int j = 0; j < 8; ++j) bb1[j] = b1[c*8 + j] * TWO_LOG2E;
        float w2[8];
        #pragma unroll
        for (int j = 0; j < 8; ++j) w2[j] = W2[c*8 + j] * TWO_LOG2E;
        const float b2s = b2[c] * TWO_LOG2E;

        #pragma unroll
        for (int k = 0; k < 4; ++k) {
            const int t = t0 + 64 * k;
            if (t >= total) break;
            const int e  = t >> 2;
            const int r0 = eidx[e];
            const int c0 = eidx1[e];
            const float2 mcv = *(const float2*)(m + (unsigned)c0 * 8u + cc2);
            const float2 mrv = *(const float2*)(m + (unsigned)r0 * 8u + cc2);
            float o = b2s;
            #pragma unroll
            for (int j = 0; j < 8; ++j) {
                float h = bb1[j];
                h = fmaf(mcv.x, w1[j],      h);
                h = fmaf(mcv.y, w1[8 + j],  h);
                h = fmaf(mrv.x, w1[16 + j], h);
                h = fmaf(mrv.y, w1[24 + j], h);
                const float e1 = __builtin_amdgcn_exp2f(h);
                const float r1 = __builtin_amdgcn_rcpf(e1 + 1.0f);
                o = fmaf(fmaf(-2.0f, r1, 1.0f), w2[j], o);
            }
            const float e2 = __builtin_amdgcn_exp2f(o);
            const float r2 = __builtin_amdgcn_rcpf(e2 + 1.0f);
            const float eo = __builtin_amdgcn_exp2f(fmaf(-TWO_LOG2E, r2, LOG2E));
            float s = eo + dpp_qperm<0xB1>(eo);
            s = s + dpp_qperm<0x4E>(s);
            out[t] = eo * __builtin_amdgcn_rcpf(s);
        }
    }
}

extern "C" void kernel_launch(void* const* d_in, const int* in_sizes, int n_in,
                              void* d_out, int out_size, void* d_ws, size_t ws_size,
                              hipStream_t stream) {
    const float* m  = (const float*)d_in[0];
    const int* eidx = (const int*)d_in[1];
    const float* W1 = (const float*)d_in[2];
    const float* b1 = (const float*)d_in[3];
    const float* W2 = (const float*)d_in[4];
    const float* b2 = (const float*)d_in[5];
    float* out = (float*)d_out;
    const int nE = in_sizes[1] / 2;

    const int total  = nE * 4;                  // 12.8M items
    const int blocks = (total + 511) / 512;     // 512 items per 128-thread block
    hipLaunchKernelGGL(edge_mlp, dim3(blocks), dim3(128), 0, stream,
                       m, eidx, W1, b1, W2, b2, out, nE);
}

// Round 8
// 70.181 us; speedup vs baseline: 1.1713x; 1.1713x over previous
//
#include <hip/hip_runtime.h>

#define TWO_LOG2E 2.8853901817779268f   // 2*log2(e)
#define LOG2E     1.4426950408889634f

typedef float f32x4 __attribute__((ext_vector_type(4)));  // native vector (nontemporal-ok)

// Thread = edge. Weights are read at wave-UNIFORM addresses -> compiler promotes
// them to s_load/SGPRs (R6 showed per-lane vector weight reloads dominate the
// loop). All 4 class MLPs computed in-thread (4 independent trans chains = ILP),
// softmax is thread-local, output is one coalesced float4 store per edge.
__global__ __launch_bounds__(256) void edge_mlp(
    const float* __restrict__ m,     // [N_NODES, 4, 2]
    const int*   __restrict__ eidx,  // [2, E]
    const float* __restrict__ W1,    // [4, 4, 8]
    const float* __restrict__ b1,    // [4, 8]
    const float* __restrict__ W2,    // [4, 8, 1]
    const float* __restrict__ b2,    // [4, 1]
    float*       __restrict__ out,   // [E, 4]
    const int nE)
{
    const int tid    = blockIdx.x * blockDim.x + threadIdx.x;
    const int stride = gridDim.x * blockDim.x;
    const int* eidx1 = eidx + nE;

    for (int e0 = tid; e0 < nE; e0 += 2 * stride) {
        #pragma unroll
        for (int k = 0; k < 2; ++k) {
            const int e = e0 + k * stride;
            if (e >= nE) break;
            const int r0 = __builtin_nontemporal_load(eidx  + e);
            const int c0 = __builtin_nontemporal_load(eidx1 + e);
            // full node rows: all 4 classes x 2 feats (32B each)
            const f32x4 ca = *(const f32x4*)(m + (unsigned)c0 * 8u);
            const f32x4 cb = *(const f32x4*)(m + (unsigned)c0 * 8u + 4);
            const f32x4 ra = *(const f32x4*)(m + (unsigned)r0 * 8u);
            const f32x4 rb = *(const f32x4*)(m + (unsigned)r0 * 8u + 4);

            const float mcx[4] = {ca.x, ca.z, cb.x, cb.z};
            const float mcy[4] = {ca.y, ca.w, cb.y, cb.w};
            const float mrx[4] = {ra.x, ra.z, rb.x, rb.z};
            const float mry[4] = {ra.y, ra.w, rb.y, rb.w};

            float eo[4];
            float s = 0.0f;
            #pragma unroll
            for (int c = 0; c < 4; ++c) {       // weights: uniform addrs -> SGPR
                float o = b2[c];
                #pragma unroll
                for (int j = 0; j < 8; ++j) {
                    float h = b1[c * 8 + j];
                    h = fmaf(mcx[c], W1[c * 32 +      j], h);
                    h = fmaf(mcy[c], W1[c * 32 +  8 + j], h);
                    h = fmaf(mrx[c], W1[c * 32 + 16 + j], h);
                    h = fmaf(mry[c], W1[c * 32 + 24 + j], h);
                    // tanh(h) = 1 - 2/(e^{2h}+1)
                    const float ex = __builtin_amdgcn_exp2f(h * TWO_LOG2E);
                    const float rr = __builtin_amdgcn_rcpf(ex + 1.0f);
                    o = fmaf(fmaf(-2.0f, rr, 1.0f), W2[c * 8 + j], o);
                }
                // eo = e^{tanh(o)} = 2^{LOG2E - TWO_LOG2E * rcp(e^{2o}+1)}
                const float e2 = __builtin_amdgcn_exp2f(o * TWO_LOG2E);
                const float r2 = __builtin_amdgcn_rcpf(e2 + 1.0f);
                eo[c] = __builtin_amdgcn_exp2f(fmaf(-TWO_LOG2E, r2, LOG2E));
                s += eo[c];
            }
            const float rs = __builtin_amdgcn_rcpf(s);
            f32x4 res;
            res.x = eo[0] * rs; res.y = eo[1] * rs;
            res.z = eo[2] * rs; res.w = eo[3] * rs;
            __builtin_nontemporal_store(res, reinterpret_cast<f32x4*>(out) + e);
        }
    }
}

extern "C" void kernel_launch(void* const* d_in, const int* in_sizes, int n_in,
                              void* d_out, int out_size, void* d_ws, size_t ws_size,
                              hipStream_t stream) {
    const float* m  = (const float*)d_in[0];
    const int* eidx = (const int*)d_in[1];
    const float* W1 = (const float*)d_in[2];
    const float* b1 = (const float*)d_in[3];
    const float* W2 = (const float*)d_in[4];
    const float* b2 = (const float*)d_in[5];
    float* out = (float*)d_out;
    const int nE = in_sizes[1] / 2;   // 3.2M edges

    const int threads = 256;
    const int blocks  = 2048;         // grid-stride: ~6 edges per thread
    hipLaunchKernelGGL(edge_mlp, dim3(blocks), dim3(threads), 0, stream,
                       m, eidx, W1, b1, W2, b2, out, nE);
}

// Round 9
// 67.822 us; speedup vs baseline: 1.2120x; 1.0348x over previous
//
#include <hip/hip_runtime.h>

#define TWO_LOG2E 2.8853901817779268f   // 2*log2(e)
#define LOG2E     1.4426950408889634f

typedef float f32x2 __attribute__((ext_vector_type(2)));

// quad_perm DPP cross-lane (VALU pipe)
template<int CTRL>
__device__ __forceinline__ float dpp_qperm(float x) {
    int r = __builtin_amdgcn_update_dpp(0, __float_as_int(x), CTRL, 0xF, 0xF, true);
    return __int_as_float(r);
}

// One thread per (edge, class); lane's class c = tid & 3.
// Trans-op diet (R8 analysis: kernel is transcendental-issue-bound at ~16cyc/op):
//  - paired tanh: one rcp serves two j's via inv = rcp((1+E0)(1+E1))
//  - softmax numerator e^{tanh(o)}: |arg|<1 -> deg-6 Taylor (6 FMA, no trans)
//  - o0 = 2log2e*(b2 + sum W2) folded; o accumulates w2n_j * r_j only.
// 15 trans/item (was 19).
__global__ __launch_bounds__(256) void edge_mlp(
    const float* __restrict__ m,     // [N_NODES, 4, 2]
    const int*   __restrict__ eidx,  // [2, E]
    const float* __restrict__ W1,    // [4, 4, 8]
    const float* __restrict__ b1,    // [4, 8]
    const float* __restrict__ W2,    // [4, 8, 1]
    const float* __restrict__ b2,    // [4, 1]
    float*       __restrict__ out,   // [E, 4]
    const int nE)
{
    const int tid0 = blockIdx.x * blockDim.x + threadIdx.x;
    const int c = tid0 & 3;
    const int cc2 = c * 2;

    // ---- per-class weights, prescaled ----
    float w1[32];                       // W1[c][i][j]*2log2e at w1[i*8+j]
    #pragma unroll
    for (int k = 0; k < 8; ++k) {
        float4 v = *(const float4*)(W1 + c*32 + 4*k);
        w1[4*k+0] = v.x * TWO_LOG2E; w1[4*k+1] = v.y * TWO_LOG2E;
        w1[4*k+2] = v.z * TWO_LOG2E; w1[4*k+3] = v.w * TWO_LOG2E;
    }
    float bb1[8];
    #pragma unroll
    for (int j = 0; j < 8; ++j) bb1[j] = b1[c*8 + j] * TWO_LOG2E;
    float w2n[8];                       // -2*2log2e*W2
    float w2sum = 0.0f;
    #pragma unroll
    for (int j = 0; j < 8; ++j) {
        const float w = W2[c*8 + j];
        w2n[j] = -2.0f * TWO_LOG2E * w;
        w2sum += w;
    }
    const float o0 = TWO_LOG2E * (b2[c] + w2sum);   // scaled-domain bias

    const int* eidx1 = eidx + nE;
    const int total  = nE * 4;
    const int stride = gridDim.x * blockDim.x;   // multiple of 4 -> c constant

    constexpr int UN = 8;
    int t = tid0;

    for (; t + (UN - 1) * stride < total; t += UN * stride) {
        int row[UN], col[UN];
        #pragma unroll
        for (int k = 0; k < UN; ++k) {
            const int e = (t + k * stride) >> 2;
            row[k] = __builtin_nontemporal_load(eidx  + e);
            col[k] = __builtin_nontemporal_load(eidx1 + e);
        }
        f32x2 mc[UN], mr[UN];
        #pragma unroll
        for (int k = 0; k < UN; ++k) {
            mc[k] = *(const f32x2*)(m + (unsigned)col[k] * 8u + cc2);
            mr[k] = *(const f32x2*)(m + (unsigned)row[k] * 8u + cc2);
        }
        #pragma unroll
        for (int k = 0; k < UN; ++k) {
            float o = o0;                         // scaled domain
            #pragma unroll
            for (int j = 0; j < 8; j += 2) {      // paired tanh: 1 rcp / 2 j's
                float h0 = bb1[j], h1 = bb1[j+1];
                h0 = fmaf(mc[k].x, w1[j],      h0); h1 = fmaf(mc[k].x, w1[j+1],    h1);
                h0 = fmaf(mc[k].y, w1[8 + j],  h0); h1 = fmaf(mc[k].y, w1[9 + j],  h1);
                h0 = fmaf(mr[k].x, w1[16 + j], h0); h1 = fmaf(mr[k].x, w1[17 + j], h1);
                h0 = fmaf(mr[k].y, w1[24 + j], h0); h1 = fmaf(mr[k].y, w1[25 + j], h1);
                const float a0 = __builtin_amdgcn_exp2f(h0) + 1.0f;   // 1+e^{2x0}
                const float a1 = __builtin_amdgcn_exp2f(h1) + 1.0f;
                const float inv = __builtin_amdgcn_rcpf(a0 * a1);
                o = fmaf(w2n[j],   inv * a1, o);  // r0 = inv*a1
                o = fmaf(w2n[j+1], inv * a0, o);  // r1 = inv*a0
            }
            const float e2 = __builtin_amdgcn_exp2f(o);
            const float r2 = __builtin_amdgcn_rcpf(e2 + 1.0f);
            const float y  = fmaf(-2.0f, r2, 1.0f);        // tanh(o_true), |y|<1
            // e^y via deg-6 Taylor (abs err ~2e-4)
            float p = fmaf(y, 0.0013888889f, 0.0083333333f);
            p = fmaf(p, y, 0.0416666667f);
            p = fmaf(p, y, 0.1666666667f);
            p = fmaf(p, y, 0.5f);
            p = fmaf(p, y, 1.0f);
            p = fmaf(p, y, 1.0f);
            float s = p + dpp_qperm<0xB1>(p);     // quad softmax denom
            s = s + dpp_qperm<0x4E>(s);
            __builtin_nontemporal_store(p * __builtin_amdgcn_rcpf(s),
                                        out + (t + k * stride));
        }
    }

    // tail
    for (; t < total; t += stride) {
        const int e  = t >> 2;
        const int r0 = eidx[e];
        const int c0 = eidx1[e];
        const f32x2 mcv = *(const f32x2*)(m + (unsigned)c0 * 8u + cc2);
        const f32x2 mrv = *(const f32x2*)(m + (unsigned)r0 * 8u + cc2);
        float o = o0;
        #pragma unroll
        for (int j = 0; j < 8; j += 2) {
            float h0 = bb1[j], h1 = bb1[j+1];
            h0 = fmaf(mcv.x, w1[j],      h0); h1 = fmaf(mcv.x, w1[j+1],    h1);
            h0 = fmaf(mcv.y, w1[8 + j],  h0); h1 = fmaf(mcv.y, w1[9 + j],  h1);
            h0 = fmaf(mrv.x, w1[16 + j], h0); h1 = fmaf(mrv.x, w1[17 + j], h1);
            h0 = fmaf(mrv.y, w1[24 + j], h0); h1 = fmaf(mrv.y, w1[25 + j], h1);
            const float a0 = __builtin_amdgcn_exp2f(h0) + 1.0f;
            const float a1 = __builtin_amdgcn_exp2f(h1) + 1.0f;
            const float inv = __builtin_amdgcn_rcpf(a0 * a1);
            o = fmaf(w2n[j],   inv * a1, o);
            o = fmaf(w2n[j+1], inv * a0, o);
        }
        const float e2 = __builtin_amdgcn_exp2f(o);
        const float r2 = __builtin_amdgcn_rcpf(e2 + 1.0f);
        const float y  = fmaf(-2.0f, r2, 1.0f);
        float p = fmaf(y, 0.0013888889f, 0.0083333333f);
        p = fmaf(p, y, 0.0416666667f);
        p = fmaf(p, y, 0.1666666667f);
        p = fmaf(p, y, 0.5f);
        p = fmaf(p, y, 1.0f);
        p = fmaf(p, y, 1.0f);
        float s = p + dpp_qperm<0xB1>(p);
        s = s + dpp_qperm<0x4E>(s);
        out[t] = p * __builtin_amdgcn_rcpf(s);
    }
}

extern "C" void kernel_launch(void* const* d_in, const int* in_sizes, int n_in,
                              void* d_out, int out_size, void* d_ws, size_t ws_size,
                              hipStream_t stream) {
    const float* m  = (const float*)d_in[0];
    const int* eidx = (const int*)d_in[1];
    const float* W1 = (const float*)d_in[2];
    const float* b1 = (const float*)d_in[3];
    const float* W2 = (const float*)d_in[4];
    const float* b2 = (const float*)d_in[5];
    float* out = (float*)d_out;
    const int nE = in_sizes[1] / 2;

    const int threads = 256;
    const int blocks  = 2048;
    hipLaunchKernelGGL(edge_mlp, dim3(blocks), dim3(threads), 0, stream,
                       m, eidx, W1, b1, W2, b2, out, nE);
}

// Round 10
// 56.480 us; speedup vs baseline: 1.4554x; 1.2008x over previous
//
#include <hip/hip_runtime.h>

#define TWO_LOG2E 2.8853901817779268f   // 2*log2(e)
#define LOG2E     1.4426950408889634f

typedef float f32x2 __attribute__((ext_vector_type(2)));
typedef float f32x4 __attribute__((ext_vector_type(4)));

// quad_perm DPP cross-lane (VALU pipe)
template<int CTRL>
__device__ __forceinline__ float dpp_qperm(float x) {
    int r = __builtin_amdgcn_update_dpp(0, __float_as_int(x), CTRL, 0xF, 0xF, true);
    return __int_as_float(r);
}

// One thread per (edge, class); lane's class c = tid & 3.
// WEIGHTS IN LDS: R2-R9 showed the allocator re-loads all 49 weight floats from
// global per iteration (VGPR=44), doubling L1/TA traffic that the divergent
// gathers need. LDS reads ride the separate DS pipe, broadcast free across the
// 16 lanes sharing a class, and leave L1 to idx/gather/store only.
__global__ __launch_bounds__(256) void edge_mlp(
    const float* __restrict__ m,     // [N_NODES, 4, 2]
    const int*   __restrict__ eidx,  // [2, E]
    const float* __restrict__ W1,    // [4, 4, 8]
    const float* __restrict__ b1,    // [4, 8]
    const float* __restrict__ W2,    // [4, 8, 1]
    const float* __restrict__ b2,    // [4, 1]
    float*       __restrict__ out,   // [E, 4]
    const int nE)
{
    // sw1[c][j][i] = W1[c][i][j]*2log2e  (ds_read_b128 per j)
    __shared__ __align__(16) float sw1[128];
    // sbw[c][j] = {b1[c][j]*2log2e, -2*2log2e*W2[c][j]}  (ds_read_b64 per j)
    __shared__ __align__(8)  float sbw[64];
    __shared__ float so0[4];         // 2log2e*(b2[c] + sum_j W2[c][j])

    const int tidb = threadIdx.x;
    if (tidb < 128) {
        const int c = tidb >> 5, q = tidb & 31, j = q >> 2, i = q & 3;
        sw1[tidb] = W1[c * 32 + i * 8 + j] * TWO_LOG2E;
    } else if (tidb < 192) {
        const int q = tidb - 128, c = q >> 4, r = q & 15, j = r >> 1;
        sbw[q] = (r & 1) ? W2[c * 8 + j] * (-2.0f * TWO_LOG2E)
                         : b1[c * 8 + j] * TWO_LOG2E;
    } else if (tidb < 196) {
        const int c = tidb - 192;
        float s = b2[c];
        #pragma unroll
        for (int j = 0; j < 8; ++j) s += W2[c * 8 + j];
        so0[c] = s * TWO_LOG2E;
    }
    __syncthreads();

    const int tid0 = blockIdx.x * blockDim.x + threadIdx.x;
    const int c = tid0 & 3;
    const int cc2 = c * 2;
    const float* w1c = sw1 + c * 32;
    const float* bwc = sbw + c * 16;
    const float o0 = so0[c];

    const int* eidx1 = eidx + nE;
    const int total  = nE * 4;
    const int stride = gridDim.x * blockDim.x;   // multiple of 4 -> c constant

    constexpr int UN = 4;
    int t = tid0;

    for (; t + (UN - 1) * stride < total; t += UN * stride) {
        int row[UN], col[UN];
        #pragma unroll
        for (int k = 0; k < UN; ++k) {
            const int e = (t + k * stride) >> 2;
            row[k] = __builtin_nontemporal_load(eidx  + e);
            col[k] = __builtin_nontemporal_load(eidx1 + e);
        }
        f32x2 mc[UN], mr[UN];
        #pragma unroll
        for (int k = 0; k < UN; ++k) {
            mc[k] = *(const f32x2*)(m + (unsigned)col[k] * 8u + cc2);
            mr[k] = *(const f32x2*)(m + (unsigned)row[k] * 8u + cc2);
        }
        #pragma unroll
        for (int k = 0; k < UN; ++k) {
            float o = o0;                          // scaled domain (x 2log2e)
            #pragma unroll
            for (int j = 0; j < 8; j += 2) {       // paired: 1 rcp / 2 j's
                const f32x4 Wa  = *(const f32x4*)(w1c + j * 4);
                const f32x4 Wb  = *(const f32x4*)(w1c + j * 4 + 4);
                const f32x2 bwa = *(const f32x2*)(bwc + j * 2);
                const f32x2 bwb = *(const f32x2*)(bwc + j * 2 + 2);
                float h0 = bwa.x, h1 = bwb.x;
                h0 = fmaf(mc[k].x, Wa.x, h0);  h1 = fmaf(mc[k].x, Wb.x, h1);
                h0 = fmaf(mc[k].y, Wa.y, h0);  h1 = fmaf(mc[k].y, Wb.y, h1);
                h0 = fmaf(mr[k].x, Wa.z, h0);  h1 = fmaf(mr[k].x, Wb.z, h1);
                h0 = fmaf(mr[k].y, Wa.w, h0);  h1 = fmaf(mr[k].y, Wb.w, h1);
                const float a0 = __builtin_amdgcn_exp2f(h0) + 1.0f;   // 1+e^{2x}
                const float a1 = __builtin_amdgcn_exp2f(h1) + 1.0f;
                const float inv = __builtin_amdgcn_rcpf(a0 * a1);
                o = fmaf(bwa.y, inv * a1, o);      // w2n0 * r0
                o = fmaf(bwb.y, inv * a0, o);      // w2n1 * r1
            }
            const float e2 = __builtin_amdgcn_exp2f(o);
            const float r2 = __builtin_amdgcn_rcpf(e2 + 1.0f);
            const float y  = fmaf(-2.0f, r2, 1.0f);       // tanh(o_true), |y|<1
            // e^y via deg-6 Taylor (abs err ~2e-4)
            float p = fmaf(y, 0.0013888889f, 0.0083333333f);
            p = fmaf(p, y, 0.0416666667f);
            p = fmaf(p, y, 0.1666666667f);
            p = fmaf(p, y, 0.5f);
            p = fmaf(p, y, 1.0f);
            p = fmaf(p, y, 1.0f);
            float s = p + dpp_qperm<0xB1>(p);      // quad softmax denom
            s = s + dpp_qperm<0x4E>(s);
            __builtin_nontemporal_store(p * __builtin_amdgcn_rcpf(s),
                                        out + (t + k * stride));
        }
    }

    // tail
    for (; t < total; t += stride) {
        const int e  = t >> 2;
        const int r0 = eidx[e];
        const int c0 = eidx1[e];
        const f32x2 mcv = *(const f32x2*)(m + (unsigned)c0 * 8u + cc2);
        const f32x2 mrv = *(const f32x2*)(m + (unsigned)r0 * 8u + cc2);
        float o = o0;
        #pragma unroll
        for (int j = 0; j < 8; j += 2) {
            const f32x4 Wa  = *(const f32x4*)(w1c + j * 4);
            const f32x4 Wb  = *(const f32x4*)(w1c + j * 4 + 4);
            const f32x2 bwa = *(const f32x2*)(bwc + j * 2);
            const f32x2 bwb = *(const f32x2*)(bwc + j * 2 + 2);
            float h0 = bwa.x, h1 = bwb.x;
            h0 = fmaf(mcv.x, Wa.x, h0);  h1 = fmaf(mcv.x, Wb.x, h1);
            h0 = fmaf(mcv.y, Wa.y, h0);  h1 = fmaf(mcv.y, Wb.y, h1);
            h0 = fmaf(mrv.x, Wa.z, h0);  h1 = fmaf(mrv.x, Wb.z, h1);
            h0 = fmaf(mrv.y, Wa.w, h0);  h1 = fmaf(mrv.y, Wb.w, h1);
            const float a0 = __builtin_amdgcn_exp2f(h0) + 1.0f;
            const float a1 = __builtin_amdgcn_exp2f(h1) + 1.0f;
            const float inv = __builtin_amdgcn_rcpf(a0 * a1);
            o = fmaf(bwa.y, inv * a1, o);
            o = fmaf(bwb.y, inv * a0, o);
        }
        const float e2 = __builtin_amdgcn_exp2f(o);
        const float r2 = __builtin_amdgcn_rcpf(e2 + 1.0f);
        const float y  = fmaf(-2.0f, r2, 1.0f);
        float p = fmaf(y, 0.0013888889f, 0.0083333333f);
        p = fmaf(p, y, 0.0416666667f);
        p = fmaf(p, y, 0.1666666667f);
        p = fmaf(p, y, 0.5f);
        p = fmaf(p, y, 1.0f);
        p = fmaf(p, y, 1.0f);
        float s = p + dpp_qperm<0xB1>(p);
        s = s + dpp_qperm<0x4E>(s);
        out[t] = p * __builtin_amdgcn_rcpf(s);
    }
}

extern "C" void kernel_launch(void* const* d_in, const int* in_sizes, int n_in,
                              void* d_out, int out_size, void* d_ws, size_t ws_size,
                              hipStream_t stream) {
    const float* m  = (const float*)d_in[0];
    const int* eidx = (const int*)d_in[1];
    const float* W1 = (const float*)d_in[2];
    const float* b1 = (const float*)d_in[3];
    const float* W2 = (const float*)d_in[4];
    const float* b2 = (const float*)d_in[5];
    float* out = (float*)d_out;
    const int nE = in_sizes[1] / 2;

    const int threads = 256;
    const int blocks  = 2048;
    hipLaunchKernelGGL(edge_mlp, dim3(blocks), dim3(threads), 0, stream,
                       m, eidx, W1, b1, W2, b2, out, nE);
}